// Round 1
// 4373.352 us; speedup vs baseline: 1.2148x; 1.2148x over previous
//
#include <hip/hip_runtime.h>
#include <math.h>

#define B 8
#define P 2048
#define D 64
#define EPS 0.1f
#define INVEPS 10.0f
#define MAXIT 100
#define THRESH 0.1f
#define RSLAB 8                    // rows staged in LDS per slab
#define ROWS_PER_BLK 32            // 4 slabs per block
#define NBLK_A (B * P / ROWS_PER_BLK)   // 512 blocks
#define PLANES (P / ROWS_PER_BLK)       // 64 partial planes per batch

// ---------------- C build: C[b,i,j] = sum_d (x[b,i,d]-y[b,j,d])^2 ----------
__global__ __launch_bounds__(256) void build_C(const float* __restrict__ x,
                                               const float* __restrict__ y,
                                               float* __restrict__ C) {
    __shared__ float xs[64 * 68];
    __shared__ float ys[64 * 68];
    const int tid = threadIdx.x;
    const int blk = blockIdx.x;        // 8 * 32 * 32 = 8192 blocks
    const int b   = blk >> 10;
    const int rem = blk & 1023;
    const int i0  = (rem >> 5) << 6;
    const int j0  = (rem & 31) << 6;

    const float4* xg = (const float4*)(x + ((size_t)(b * P + i0)) * D);
    const float4* yg = (const float4*)(y + ((size_t)(b * P + j0)) * D);
#pragma unroll
    for (int p = 0; p < 4; ++p) {
        int q = tid + (p << 8);
        int row = q >> 4, c4 = q & 15;
        float4 xv = xg[row * 16 + c4];
        float4 yv = yg[row * 16 + c4];
        float* xd = &xs[row * 68 + (c4 << 2)];
        xd[0] = xv.x; xd[1] = xv.y; xd[2] = xv.z; xd[3] = xv.w;
        float* yd = &ys[row * 68 + (c4 << 2)];
        yd[0] = yv.x; yd[1] = yv.y; yd[2] = yv.z; yd[3] = yv.w;
    }
    __syncthreads();

    const int ti = tid >> 4, tj = tid & 15;
    float acc[4][4] = {};
#pragma unroll 4
    for (int d4 = 0; d4 < 16; ++d4) {
        float4 xa[4], yb[4];
#pragma unroll
        for (int a = 0; a < 4; ++a)
            xa[a] = *(const float4*)&xs[(ti * 4 + a) * 68 + (d4 << 2)];
#pragma unroll
        for (int bb = 0; bb < 4; ++bb)
            yb[bb] = *(const float4*)&ys[(tj * 4 + bb) * 68 + (d4 << 2)];
#pragma unroll
        for (int a = 0; a < 4; ++a)
#pragma unroll
            for (int bb = 0; bb < 4; ++bb) {
                float dx = xa[a].x - yb[bb].x;
                float dy = xa[a].y - yb[bb].y;
                float dz = xa[a].z - yb[bb].z;
                float dw = xa[a].w - yb[bb].w;
                acc[a][bb] += dx * dx + dy * dy + dz * dz + dw * dw;
            }
    }
    size_t base = ((size_t)b * P + (i0 + ti * 4)) * P + (j0 + tj * 4);
#pragma unroll
    for (int a = 0; a < 4; ++a) {
        float4 o = make_float4(acc[a][0], acc[a][1], acc[a][2], acc[a][3]);
        *(float4*)&C[base + (size_t)a * P] = o;
    }
}

// ---------------- online logsumexp helpers --------------------------------
__device__ __forceinline__ void lse_push(float z, float& m, float& s) {
    if (z > m) { s = s * __expf(m - z) + 1.0f; m = z; }
    else       { s += __expf(z - m); }
}
__device__ __forceinline__ void lse_merge(float mo, float so, float& m, float& s) {
    float M = fmaxf(m, mo);
    s = s * __expf(m - M) + so * __expf(mo - M);
    m = M;
}

// ---------------- init: zero u, v, err accumulators, done flags, cost ------
__global__ void init_ws(float* __restrict__ u, float* __restrict__ v,
                        float* __restrict__ errAcc, unsigned* __restrict__ doneArr,
                        float* __restrict__ cost) {
    int idx = blockIdx.x * blockDim.x + threadIdx.x;
    if (idx < B * P) { u[idx] = 0.0f; v[idx] = 0.0f; }
    if (idx < MAXIT) errAcc[idx] = 0.0f;
    if (idx <= MAXIT) doneArr[idx] = 0u;
    if (idx < B) cost[idx] = 0.0f;
}

// ---- iteration kernel A: row-LSE (u update + err) then column partials ----
// block = 512 threads = 8 waves; owns 32 rows of one batch, processed as
// 4 slabs of 8 rows staged through 64 KB LDS. v staged in LDS once.
// Software-pipelined: the NEXT slab's row is prefetched into 8 float4
// registers right after the mid-slab barrier, so its global loads are in
// flight during the entire LDS-resident col phase. The vmcnt(0) drain at
// the end-of-slab __syncthreads then finds them (mostly) complete ->
// memory and compute phases overlap instead of strictly alternating.
__global__ __launch_bounds__(512, 4) void iter_rowcol(
        const float* __restrict__ C, const float* __restrict__ vg,
        float* __restrict__ u, float2* __restrict__ part,
        float* __restrict__ errAcc, const unsigned* __restrict__ doneArr, int t) {
    if (doneArr[t]) return;
    __shared__ float sC[RSLAB * P];   // 64 KB: current slab's rows
    __shared__ float sv[P];           // 8 KB: this batch's v
    __shared__ float su[RSLAB];
    __shared__ float serr[8];
    const int tid = threadIdx.x, lane = tid & 63, wid = tid >> 6;  // 8 waves
    const int b  = blockIdx.x >> 6;       // 64 blocks per batch
    const int q  = blockIdx.x & 63;       // row-block within batch
    const int r0 = q * ROWS_PER_BLK;
    const float* Cb = C + (size_t)b * P * P;
    const float eps_logmu = EPS * logf(1.0f / (float)P + 1e-8f);

    // stage v for this batch: 512 threads x 1 float4
    ((float4*)sv)[tid] = ((const float4*)(vg + (size_t)b * P))[tid];

    // prefetch slab 0: wave `wid` owns row r0 + wid (8 float4 per lane)
    float4 pf[8];
    {
        const float4* Crow0 = (const float4*)(Cb + (size_t)(r0 + wid) * P);
#pragma unroll
        for (int k = 0; k < 8; ++k) pf[k] = Crow0[lane + (k << 6)];
    }

    float cm[4], cs[4];                   // col chains: cols 4*tid..+3
#pragma unroll
    for (int k = 0; k < 4; ++k) { cm[k] = -INFINITY; cs[k] = 0.0f; }
    float werr = 0.0f;
    __syncthreads();                      // sv ready

#pragma unroll
    for (int sl = 0; sl < 4; ++sl) {
        // ---- row phase: wave `wid` handles row r0 + 8*sl + wid (from pf) --
        const int r = r0 + sl * RSLAB + wid;
        float4* lrow = (float4*)&sC[wid * P];
        float rm[4] = {-INFINITY, -INFINITY, -INFINITY, -INFINITY};
        float rs[4] = {0.0f, 0.0f, 0.0f, 0.0f};
#pragma unroll
        for (int k = 0; k < 8; ++k) {
            int it = lane + (k << 6);
            float4 c4 = pf[k];
            lrow[it] = c4;                // stage for col phase
            float4 v4 = ((const float4*)sv)[it];
            lse_push((v4.x - c4.x) * INVEPS, rm[0], rs[0]);
            lse_push((v4.y - c4.y) * INVEPS, rm[1], rs[1]);
            lse_push((v4.z - c4.z) * INVEPS, rm[2], rs[2]);
            lse_push((v4.w - c4.w) * INVEPS, rm[3], rs[3]);
        }
        lse_merge(rm[1], rs[1], rm[0], rs[0]);
        lse_merge(rm[3], rs[3], rm[2], rs[2]);
        lse_merge(rm[2], rs[2], rm[0], rs[0]);
#pragma unroll
        for (int off = 32; off; off >>= 1) {
            float mo = __shfl_xor(rm[0], off, 64);
            float so = __shfl_xor(rs[0], off, 64);
            lse_merge(mo, so, rm[0], rs[0]);
        }
        float unew = eps_logmu - EPS * (rm[0] + logf(rs[0]));
        if (lane == 0) {
            int gi = b * P + r;
            werr += fabsf(unew - u[gi]);
            u[gi] = unew;
            su[wid] = unew;
        }
        __syncthreads();                  // sC + su ready

        // ---- issue prefetch for slab sl+1 (in flight during col phase) ----
        if (sl < 3) {
            const float4* Crown = (const float4*)(Cb + (size_t)(r + RSLAB) * P);
#pragma unroll
            for (int k = 0; k < 8; ++k) pf[k] = Crown[lane + (k << 6)];
        }

        // ---- col phase: 512 threads x 4 cols, 8 rows from LDS ----
#pragma unroll
        for (int rr = 0; rr < RSLAB; ++rr) {
            float ur = su[rr];
            float4 c4 = *(const float4*)&sC[rr * P + (tid << 2)];
            lse_push((ur - c4.x) * INVEPS, cm[0], cs[0]);
            lse_push((ur - c4.y) * INVEPS, cm[1], cs[1]);
            lse_push((ur - c4.z) * INVEPS, cm[2], cs[2]);
            lse_push((ur - c4.w) * INVEPS, cm[3], cs[3]);
        }
        __syncthreads();                  // sC/su consumed; pf drain lands here
    }

    if (lane == 0) serr[wid] = werr;
    __syncthreads();
    if (tid == 0)
        atomicAdd(&errAcc[t], serr[0] + serr[1] + serr[2] + serr[3] +
                              serr[4] + serr[5] + serr[6] + serr[7]);

    // ---- store partial plane q for batch b (coalesced float4) ----
    float2* pbase = part + ((size_t)q * B + b) * P;
    *(float4*)&pbase[(tid << 2)]     = make_float4(cm[0], cs[0], cm[1], cs[1]);
    *(float4*)&pbase[(tid << 2) + 2] = make_float4(cm[2], cs[2], cm[3], cs[3]);
}

// ---- iteration kernel B: merge 64 planes -> v; latch done flag ------------
// 256 blocks x 256 threads; a block owns 64 columns; 4 threads per column,
// each merging 16 planes (2 independent chains), then LDS tree-reduce.
// part plane layout: part[(q*B + b)*P + j] == part[q*(B*P) + idx] where
// idx = b*P + j is the global column.
__global__ __launch_bounds__(256) void iter_merge(
        const float2* __restrict__ part, float* __restrict__ vg,
        const float* __restrict__ errAcc, unsigned* __restrict__ doneArr, int t) {
    __shared__ float2 sred[3][64];
    const int tid = threadIdx.x;
    if (blockIdx.x == 0 && tid == 0) {
        // errAcc[t]==0 when frozen, so the latch self-propagates.
        doneArr[t + 1] = doneArr[t] | (errAcc[t] < THRESH * (float)B ? 1u : 0u);
    }
    if (doneArr[t]) return;
    const int cl = tid & 63;              // column within block
    const int g  = tid >> 6;              // plane group 0..3
    const size_t idx = (size_t)blockIdx.x * 64 + cl;   // global column
    float m[2] = {-INFINITY, -INFINITY}, s[2] = {0.0f, 0.0f};
#pragma unroll
    for (int k = 0; k < 8; ++k) {
#pragma unroll
        for (int c = 0; c < 2; ++c) {
            int qq = g * 16 + k * 2 + c;
            float2 pk = part[(size_t)qq * (B * P) + idx];
            lse_merge(pk.x, pk.y, m[c], s[c]);
        }
    }
    lse_merge(m[1], s[1], m[0], s[0]);
    if (g) sred[g - 1][cl] = make_float2(m[0], s[0]);
    __syncthreads();
    if (g == 0) {
#pragma unroll
        for (int gg = 0; gg < 3; ++gg) {
            float2 o = sred[gg][cl];
            lse_merge(o.x, o.y, m[0], s[0]);
        }
        const float eps_logmu = EPS * logf(1.0f / (float)P + 1e-8f);  // log_nu == log_mu
        vg[idx] = eps_logmu - EPS * (m[0] + logf(s[0]));
    }
}

// ---- final: pi = exp((u+v-C)/eps), cost[b] = sum pi*C ---------------------
// 1024 blocks * 4 waves * 4 rows = 16384 rows = B*P.
__global__ __launch_bounds__(256) void final_pi_cost(
        const float* __restrict__ C, const float* __restrict__ u,
        const float* __restrict__ vg, float* __restrict__ pi,
        float* __restrict__ cost) {
    __shared__ float sc[B];
    const int tid = threadIdx.x, lane = tid & 63, wid = tid >> 6;
    if (tid < B) sc[tid] = 0.0f;
    __syncthreads();
    const int gw = blockIdx.x * 4 + wid;      // 0..4095
    const int rbase = gw * 4;
    if (rbase >= B * P) return;               // defensive
    const int b = rbase >> 11;
    const float4* vrow = (const float4*)(vg + b * P);
    float acc = 0.0f;
    for (int k = 0; k < 4; ++k) {
        const int r = rbase + k;
        const float ur = u[r];
        const float4* Crow = (const float4*)(C + (size_t)r * P);
        float4* prow = (float4*)(pi + (size_t)r * P);
        for (int it = lane; it < P / 4; it += 64) {
            float4 c4 = Crow[it];
            float4 v4 = vrow[it];
            float4 p4;
            p4.x = __expf((ur + v4.x - c4.x) * INVEPS);
            p4.y = __expf((ur + v4.y - c4.y) * INVEPS);
            p4.z = __expf((ur + v4.z - c4.z) * INVEPS);
            p4.w = __expf((ur + v4.w - c4.w) * INVEPS);
            prow[it] = p4;
            acc += p4.x * c4.x + p4.y * c4.y + p4.z * c4.z + p4.w * c4.w;
        }
    }
#pragma unroll
    for (int off = 32; off; off >>= 1) acc += __shfl_xor(acc, off, 64);
    if (lane == 0) atomicAdd(&sc[b], acc);
    __syncthreads();
    if (tid < B && sc[tid] != 0.0f) atomicAdd(&cost[tid], sc[tid]);
}

extern "C" void kernel_launch(void* const* d_in, const int* in_sizes, int n_in,
                              void* d_out, int out_size, void* d_ws, size_t ws_size,
                              hipStream_t stream) {
    const float* x = (const float*)d_in[0];
    const float* y = (const float*)d_in[1];
    float* out  = (float*)d_out;
    float* cost = out;                              // [8]
    float* pi   = out + 8;                          // [8*2048*2048]
    float* C    = out + 8 + (size_t)B * P * P;      // [8*2048*2048]

    // Column partials live in the pi output region (scratch until final pass):
    // PLANES * B*P float2 = 8 MB << 134 MB.
    float2* part = (float2*)pi;

    float* ws      = (float*)d_ws;
    float* u       = ws;                            // B*P
    float* v       = ws + B * P;                    // B*P
    float* errAcc  = ws + 2 * B * P;                // MAXIT
    unsigned* doneArr = (unsigned*)(ws + 2 * B * P + 128);  // MAXIT+1

    hipLaunchKernelGGL(build_C, dim3(8 * 32 * 32), dim3(256), 0, stream, x, y, C);
    hipLaunchKernelGGL(init_ws, dim3(64), dim3(256), 0, stream,
                       u, v, errAcc, doneArr, cost);

    for (int t = 0; t < MAXIT; ++t) {
        hipLaunchKernelGGL(iter_rowcol, dim3(NBLK_A), dim3(512), 0, stream,
                           (const float*)C, (const float*)v, u, part,
                           errAcc, (const unsigned*)doneArr, t);
        hipLaunchKernelGGL(iter_merge, dim3(B * P / 64), dim3(256), 0, stream,
                           (const float2*)part, v, (const float*)errAcc,
                           doneArr, t);
    }

    hipLaunchKernelGGL(final_pi_cost, dim3(1024), dim3(256), 0, stream,
                       (const float*)C, (const float*)u, (const float*)v,
                       pi, cost);
}